// Round 2
// baseline (23843.744 us; speedup 1.0000x reference)
//
#include <hip/hip_runtime.h>
#include <hip/hip_bf16.h>
#include <math.h>

typedef __hip_bfloat16 bf16;

#define DIMC 1024
#define TLEN 2048
#define NBATCH 2
#define NHEADS 16
#define NE 8
#define NTOK 4096          // B*T
#define HIDN 4096          // 4*DIM
#define LNEPS 1e-5f

// flag-branched input load: f!=0 -> fp32, else bf16
__device__ __forceinline__ float ldf(const void* p, size_t i, int f) {
    return f ? ((const float*)p)[i] : __bfloat162float(((const bf16*)p)[i]);
}

// ---------------------------------------------------------------- dtype detect
// bf16 interpretation of true-bf16 data is sane (<~6); of fp32 data it has
// random exponent bits -> max over 256 elems > 1e3 w.p. ~1.
__global__ void detect_kernel(const void* x, int* flag) {
    if (threadIdx.x == 0 && blockIdx.x == 0) {
        const bf16* xb = (const bf16*)x;
        float mx = 0.f;
        for (int i = 0; i < 256; i++) {
            float v = fabsf(__bfloat162float(xb[i]));
            if (isnan(v) || isinf(v)) v = 1e30f;
            mx = fmaxf(mx, v);
        }
        flag[0] = (mx < 1e3f) ? 0 : 1;   // 1 = inputs are fp32
    }
}

// ---------------------------------------------------------------- zero init
__global__ void zero_kernel(float* moe_out, unsigned* counts) {
    int i = blockIdx.x * 256 + threadIdx.x;
    if (i < NTOK * DIMC) moe_out[i] = 0.0f;
    if (i < NE) counts[i] = 0u;
}

// ---------------------------------------------------------------- layernorm
// one block per token; input either raw (xr, flag dtype) or f32 ws (xf)
__global__ __launch_bounds__(256) void ln_kernel(const void* xr, const float* xf,
                                                 const void* g, const void* b,
                                                 float* out, const int* flag) {
    int f32 = *flag;
    int n = blockIdx.x;
    int tid = threadIdx.x;
    __shared__ float red[256];
    float v[4];
#pragma unroll
    for (int l = 0; l < 4; l++) {
        int c = l * 256 + tid;
        v[l] = xr ? ldf(xr, (size_t)n * DIMC + c, f32) : xf[(size_t)n * DIMC + c];
    }
    float s = v[0] + v[1] + v[2] + v[3];
    red[tid] = s; __syncthreads();
    for (int st = 128; st > 0; st >>= 1) { if (tid < st) red[tid] += red[tid + st]; __syncthreads(); }
    float mu = red[0] * (1.0f / DIMC);
    __syncthreads();
    float s2 = 0.f;
#pragma unroll
    for (int l = 0; l < 4; l++) { float d = v[l] - mu; s2 += d * d; }
    red[tid] = s2; __syncthreads();
    for (int st = 128; st > 0; st >>= 1) { if (tid < st) red[tid] += red[tid + st]; __syncthreads(); }
    float var = red[0] * (1.0f / DIMC);
    float rstd = rsqrtf(var + LNEPS);
#pragma unroll
    for (int l = 0; l < 4; l++) {
        int c = l * 256 + tid;
        out[(size_t)n * DIMC + c] = (v[l] - mu) * rstd * ldf(g, c, f32) + ldf(b, c, f32);
    }
}

// ---------------------------------------------------------------- fp32 GEMM
// C[M,N] = A[M,K] @ B[K,N] (+ resid). A f32 ws, B/resid raw inputs (flag dtype).
__global__ __launch_bounds__(256) void gemm_f32(const float* __restrict__ A,
                                                const void* __restrict__ B,
                                                const void* __restrict__ resid,
                                                float* __restrict__ C,
                                                int M, int N, int K, const int* flag) {
    int f32 = *flag;
    __shared__ float As[64][17];
    __shared__ float Bs[16][64];
    int tid = threadIdx.x;
    int tx = tid & 15, ty = tid >> 4;
    int n0 = blockIdx.x * 64, m0 = blockIdx.y * 64;
    float acc[4][4] = {};
    for (int kk = 0; kk < K; kk += 16) {
#pragma unroll
        for (int l = 0; l < 4; l++) {
            int idx = tid + l * 256;
            int r = idx >> 4, c = idx & 15;
            As[r][c] = A[(size_t)(m0 + r) * K + kk + c];
        }
#pragma unroll
        for (int l = 0; l < 4; l++) {
            int idx = tid + l * 256;
            int kc = idx >> 6, nn = idx & 63;
            Bs[kc][nn] = ldf(B, (size_t)(kk + kc) * N + n0 + nn, f32);
        }
        __syncthreads();
#pragma unroll
        for (int kc = 0; kc < 16; kc++) {
            float a[4], bb[4];
#pragma unroll
            for (int i = 0; i < 4; i++) a[i] = As[ty * 4 + i][kc];
#pragma unroll
            for (int j = 0; j < 4; j++) bb[j] = Bs[kc][tx * 4 + j];
#pragma unroll
            for (int i = 0; i < 4; i++)
#pragma unroll
                for (int j = 0; j < 4; j++) acc[i][j] += a[i] * bb[j];
        }
        __syncthreads();
    }
#pragma unroll
    for (int i = 0; i < 4; i++) {
        int row = m0 + ty * 4 + i;
#pragma unroll
        for (int j = 0; j < 4; j++) {
            int col = n0 + tx * 4 + j;
            float r0 = resid ? ldf(resid, (size_t)row * N + col, f32) : 0.0f;
            C[(size_t)row * N + col] = acc[i][j] + r0;
        }
    }
}

// ---------------------------------------------------------------- attention
// one wave (64 threads) per (q, b*h); online softmax over k<=q. All fp32 ws.
__global__ __launch_bounds__(64) void attn_kernel(const float* __restrict__ qkv,
                                                  float* __restrict__ y) {
    int q = blockIdx.x;
    int bh = blockIdx.y;
    int b = bh >> 4, h = bh & 15;
    int d = threadIdx.x;
    size_t nq = (size_t)b * TLEN + q;
    float qd = qkv[nq * 3 * DIMC + h * 64 + d] * 0.125f;   // 1/sqrt(64)
    const float* kbase = qkv + (size_t)b * TLEN * 3 * DIMC + DIMC + h * 64 + d;
    const float* vbase = kbase + DIMC;
    float m = -INFINITY, l = 0.f, acc = 0.f;
    for (int k = 0; k <= q; k++) {
        float p = qd * kbase[(size_t)k * 3 * DIMC];
#pragma unroll
        for (int mask = 32; mask > 0; mask >>= 1) p += __shfl_xor(p, mask);
        float vd = vbase[(size_t)k * 3 * DIMC];
        float mn = fmaxf(m, p);
        float alpha = __expf(m - mn);
        float w = __expf(p - mn);
        l = l * alpha + w;
        acc = acc * alpha + w * vd;
        m = mn;
    }
    y[nq * DIMC + h * 64 + d] = acc / l;
}

// ---------------------------------------------------------------- router
__global__ __launch_bounds__(256) void router_kernel(const float* __restrict__ h2,
                                                     const void* __restrict__ wr,
                                                     int* topi, float* topw,
                                                     unsigned* counts, const int* flag) {
    int f32 = *flag;
    int n = blockIdx.x, tid = threadIdx.x;
    __shared__ float sm[NE][256];
    float p[NE] = {};
#pragma unroll
    for (int l = 0; l < 4; l++) {
        int dd = l * 256 + tid;
        float hv = h2[(size_t)n * DIMC + dd];
#pragma unroll
        for (int e = 0; e < NE; e++) p[e] += hv * ldf(wr, (size_t)dd * NE + e, f32);
    }
#pragma unroll
    for (int e = 0; e < NE; e++) sm[e][tid] = p[e];
    __syncthreads();
    for (int st = 128; st > 0; st >>= 1) {
        if (tid < st)
#pragma unroll
            for (int e = 0; e < NE; e++) sm[e][tid] += sm[e][tid + st];
        __syncthreads();
    }
    if (tid == 0) {
        float lg[NE];
#pragma unroll
        for (int e = 0; e < NE; e++) lg[e] = sm[e][0];
        int i0 = 0;
        for (int e = 1; e < NE; e++) if (lg[e] > lg[i0]) i0 = e;        // first max
        int i1 = -1;
        for (int e = 0; e < NE; e++)
            if (e != i0 && (i1 < 0 || lg[e] > lg[i1])) i1 = e;          // second
        float e1 = __expf(lg[i1] - lg[i0]);
        float inv = 1.0f / (1.0f + e1);
        topi[n * 2] = i0; topi[n * 2 + 1] = i1;
        topw[n * 2] = inv; topw[n * 2 + 1] = e1 * inv;
        atomicAdd(&counts[i0], 1u);
        atomicAdd(&counts[i1], 1u);
    }
}

__global__ void offsets_kernel(const unsigned* counts, unsigned* offsets, unsigned* cursor) {
    if (threadIdx.x == 0 && blockIdx.x == 0) {
        unsigned s = 0;
        for (int e = 0; e < NE; e++) { offsets[e] = s; s += counts[e]; cursor[e] = 0u; }
    }
}

__global__ void scatter_kernel(const int* topi, const unsigned* offsets,
                               unsigned* cursor, int* perm) {
    int n = blockIdx.x * 256 + threadIdx.x;
    if (n >= NTOK) return;
    for (int s = 0; s < 2; s++) {
        int e = topi[n * 2 + s];
        unsigned pos = atomicAdd(&cursor[e], 1u);
        perm[offsets[e] + pos] = n * 2 + s;
    }
}

// ---------------------------------------------------------------- fused MoE
// grid (NTOK/8, E); 8 gathered rows per block; hidden in 64-chunks.
__global__ __launch_bounds__(256) void moe_kernel(const float* __restrict__ h2,
                                                  const void* __restrict__ w1,
                                                  const void* __restrict__ b1,
                                                  const void* __restrict__ w2,
                                                  const void* __restrict__ b2,
                                                  const int* __restrict__ perm,
                                                  const unsigned* __restrict__ counts,
                                                  const unsigned* __restrict__ offsets,
                                                  const float* __restrict__ topw,
                                                  float* __restrict__ moe_out,
                                                  const int* flag) {
    int f32 = *flag;
    int e = blockIdx.y;
    int cnt = (int)counts[e];
    int row0 = blockIdx.x * 8;
    if (row0 >= cnt) return;
    int tid = threadIdx.x;

    __shared__ float Xs[8][DIMC];   // 32 KB
    __shared__ float hs[8][64];
    __shared__ float wrow[8];
    __shared__ int   toks[8];

    unsigned off = offsets[e];
    if (tid < 8) {
        int rr = row0 + tid;
        int pair = (rr < cnt) ? perm[off + rr] : -1;
        toks[tid] = (pair >= 0) ? (pair >> 1) : -1;
        wrow[tid] = (pair >= 0) ? topw[pair] : 0.0f;
    }
    __syncthreads();
#pragma unroll
    for (int r = 0; r < 8; r++) {
        int tok = toks[r];
        int tsrc = (tok >= 0) ? tok : 0;
#pragma unroll
        for (int l = 0; l < 4; l++) {
            int c = l * 256 + tid;
            Xs[r][c] = h2[(size_t)tsrc * DIMC + c];
        }
    }
    __syncthreads();

    float acc[8][4] = {};
    const size_t w1e = (size_t)e * DIMC * HIDN;
    const size_t w2e = (size_t)e * HIDN * DIMC;
    int hc = tid & 63, r0 = tid >> 6;               // r0 in 0..3

    for (int hb = 0; hb < HIDN; hb += 64) {
        float d0 = 0.f, d1 = 0.f;
        size_t w1c = w1e + hb + hc;
        for (int d = 0; d < DIMC; d++) {
            float wv = ldf(w1, w1c + (size_t)d * HIDN, f32);
            d0 += Xs[r0][d] * wv;
            d1 += Xs[r0 + 4][d] * wv;
        }
        float bias = ldf(b1, (size_t)e * HIDN + hb + hc, f32);
        d0 += bias; d1 += bias;
        float g0 = 0.5f * d0 * (1.0f + erff(d0 * 0.70710678118f));   // exact gelu
        float g1 = 0.5f * d1 * (1.0f + erff(d1 * 0.70710678118f));
        __syncthreads();            // previous chunk's hs readers done
        hs[r0][hc] = g0;
        hs[r0 + 4][hc] = g1;
        __syncthreads();
        for (int j = 0; j < 64; j++) {
            float hv[8];
#pragma unroll
            for (int r = 0; r < 8; r++) hv[r] = hs[r][j];
            size_t w2r = w2e + (size_t)(hb + j) * DIMC + tid;
#pragma unroll
            for (int jc = 0; jc < 4; jc++) {
                float wv = ldf(w2, w2r + (size_t)jc * 256, f32);
#pragma unroll
                for (int r = 0; r < 8; r++) acc[r][jc] += hv[r] * wv;
            }
        }
    }

#pragma unroll
    for (int r = 0; r < 8; r++) {
        int tok = toks[r];
        if (tok < 0) continue;
        float w = wrow[r];
#pragma unroll
        for (int jc = 0; jc < 4; jc++) {
            int c = jc * 256 + tid;
            float val = (acc[r][jc] + ldf(b2, (size_t)e * DIMC + c, f32)) * w;
            atomicAdd(&moe_out[(size_t)tok * DIMC + c], val);
        }
    }
}

// ---------------------------------------------------------------- final add
__global__ void final_kernel(const float* x2, const float* moe, void* out, const int* flag) {
    int i = blockIdx.x * 256 + threadIdx.x;
    float v = x2[i] + moe[i];
    if (*flag) ((float*)out)[i] = v;
    else       ((bf16*)out)[i] = __float2bfloat16(v);
}

// ================================================================ launch
extern "C" void kernel_launch(void* const* d_in, const int* in_sizes, int n_in,
                              void* d_out, int out_size, void* d_ws, size_t ws_size,
                              hipStream_t stream) {
    const void* x      = d_in[0];
    const void* ln1_g  = d_in[1];
    const void* ln1_b  = d_in[2];
    const void* w_attn = d_in[3];
    const void* w_proj = d_in[4];
    const void* ln2_g  = d_in[5];
    const void* ln2_b  = d_in[6];
    const void* w_rout = d_in[7];
    const void* w1     = d_in[8];
    const void* b1     = d_in[9];
    const void* w2     = d_in[10];
    const void* b2     = d_in[11];

    const size_t MT = (size_t)NTOK * DIMC;   // 4 M elements
    float* ws   = (float*)d_ws;
    float* h    = ws;                // MT
    float* qkv  = ws + MT;           // 3*MT
    float* y    = ws + 4 * MT;       // MT
    float* x2   = ws + 5 * MT;       // MT
    float* h2   = ws + 6 * MT;       // MT
    float* moe  = ws + 7 * MT;       // MT
    float* small = ws + 8 * MT;
    int*      topi    = (int*)small;                   // 8192
    float*    topw    = (float*)(topi + 2 * NTOK);     // 8192
    unsigned* counts  = (unsigned*)(topw + 2 * NTOK);  // 8
    unsigned* offsets = counts + NE;                   // 8
    unsigned* cursor  = offsets + NE;                  // 8
    int*      perm    = (int*)(cursor + NE);           // 8192
    int*      flag    = (int*)(perm + 2 * NTOK);       // 1

    // 0. detect input dtype (fp32 vs bf16)
    detect_kernel<<<1, 64, 0, stream>>>(x, flag);
    // 1. zero moe accumulator + expert counts
    zero_kernel<<<dim3((MT + 255) / 256), 256, 0, stream>>>(moe, counts);
    // 2. LN1
    ln_kernel<<<NTOK, 256, 0, stream>>>(x, nullptr, ln1_g, ln1_b, h, flag);
    // 3. qkv = h @ w_attn  [4096,1024]x[1024,3072]
    gemm_f32<<<dim3(3 * DIMC / 64, NTOK / 64), 256, 0, stream>>>(h, w_attn, nullptr, qkv,
                                                                 NTOK, 3 * DIMC, DIMC, flag);
    // 4. attention
    attn_kernel<<<dim3(TLEN, NBATCH * NHEADS), 64, 0, stream>>>(qkv, y);
    // 5. x2 = x + y @ w_proj
    gemm_f32<<<dim3(DIMC / 64, NTOK / 64), 256, 0, stream>>>(y, w_proj, x, x2,
                                                             NTOK, DIMC, DIMC, flag);
    // 6. LN2
    ln_kernel<<<NTOK, 256, 0, stream>>>(nullptr, x2, ln2_g, ln2_b, h2, flag);
    // 7. router + top-2
    router_kernel<<<NTOK, 256, 0, stream>>>(h2, w_rout, topi, topw, counts, flag);
    // 8. prefix offsets
    offsets_kernel<<<1, 64, 0, stream>>>(counts, offsets, cursor);
    // 9. scatter token-slot ids by expert
    scatter_kernel<<<NTOK / 256, 256, 0, stream>>>(topi, offsets, cursor, perm);
    // 10. fused expert MLP
    moe_kernel<<<dim3(NTOK / 8, NE), 256, 0, stream>>>(h2, w1, b1, w2, b2,
                                                       perm, counts, offsets, topw, moe, flag);
    // 11. out = x2 + moe (dtype per flag)
    final_kernel<<<dim3((MT + 255) / 256), 256, 0, stream>>>(x2, moe, (void*)d_out, flag);
}

// Round 3
// 6876.741 us; speedup vs baseline: 3.4673x; 3.4673x over previous
//
#include <hip/hip_runtime.h>
#include <hip/hip_bf16.h>
#include <math.h>

typedef __hip_bfloat16 bf16;
typedef __bf16 bf16x8 __attribute__((ext_vector_type(8)));
typedef float f32x4 __attribute__((ext_vector_type(4)));

#define DIMC 1024
#define TLEN 2048
#define NBATCH 2
#define NHEADS 16
#define NE 8
#define NTOK 4096          // B*T
#define HIDN 4096          // 4*DIM
#define LNEPS 1e-5f

// flag-branched input load: f!=0 -> fp32, else bf16
__device__ __forceinline__ float ldf(const void* p, size_t i, int f) {
    return f ? ((const float*)p)[i] : __bfloat162float(((const bf16*)p)[i]);
}
__device__ __forceinline__ short f2b(float v) {
    bf16 h = __float2bfloat16(v);
    return *reinterpret_cast<short*>(&h);
}

// ---------------------------------------------------------------- dtype detect
__global__ void detect_kernel(const void* x, int* flag) {
    if (threadIdx.x == 0 && blockIdx.x == 0) {
        const bf16* xb = (const bf16*)x;
        float mx = 0.f;
        for (int i = 0; i < 256; i++) {
            float v = fabsf(__bfloat162float(xb[i]));
            if (isnan(v) || isinf(v)) v = 1e30f;
            mx = fmaxf(mx, v);
        }
        flag[0] = (mx < 1e3f) ? 0 : 1;   // 1 = inputs are fp32
    }
}

// ---------------------------------------------------------------- zero init
__global__ void zero_kernel(float* moe_out, unsigned* counts) {
    int i = blockIdx.x * 256 + threadIdx.x;
    if (i < NTOK * DIMC) moe_out[i] = 0.0f;
    if (i < NE) counts[i] = 0u;
}

// ---------------------------------------------------------------- layernorm
// one block per token; outputs fp32 (outf) and/or bf16 (outb)
__global__ __launch_bounds__(256) void ln_kernel(const void* xr, const float* xf,
                                                 const void* g, const void* b,
                                                 float* outf, short* outb,
                                                 const int* flag) {
    int f32 = *flag;
    int n = blockIdx.x;
    int tid = threadIdx.x;
    __shared__ float red[256];
    float v[4];
#pragma unroll
    for (int l = 0; l < 4; l++) {
        int c = l * 256 + tid;
        v[l] = xr ? ldf(xr, (size_t)n * DIMC + c, f32) : xf[(size_t)n * DIMC + c];
    }
    float s = v[0] + v[1] + v[2] + v[3];
    red[tid] = s; __syncthreads();
    for (int st = 128; st > 0; st >>= 1) { if (tid < st) red[tid] += red[tid + st]; __syncthreads(); }
    float mu = red[0] * (1.0f / DIMC);
    __syncthreads();
    float s2 = 0.f;
#pragma unroll
    for (int l = 0; l < 4; l++) { float d = v[l] - mu; s2 += d * d; }
    red[tid] = s2; __syncthreads();
    for (int st = 128; st > 0; st >>= 1) { if (tid < st) red[tid] += red[tid + st]; __syncthreads(); }
    float var = red[0] * (1.0f / DIMC);
    float rstd = rsqrtf(var + LNEPS);
#pragma unroll
    for (int l = 0; l < 4; l++) {
        int c = l * 256 + tid;
        float o = (v[l] - mu) * rstd * ldf(g, c, f32) + ldf(b, c, f32);
        if (outf) outf[(size_t)n * DIMC + c] = o;
        if (outb) outb[(size_t)n * DIMC + c] = f2b(o);
    }
}

// ---------------------------------------------------------------- fp32 GEMM (qkv / proj, unchanged)
__global__ __launch_bounds__(256) void gemm_f32(const float* __restrict__ A,
                                                const void* __restrict__ B,
                                                const void* __restrict__ resid,
                                                float* __restrict__ C,
                                                int M, int N, int K, const int* flag) {
    int f32 = *flag;
    __shared__ float As[64][17];
    __shared__ float Bs[16][64];
    int tid = threadIdx.x;
    int tx = tid & 15, ty = tid >> 4;
    int n0 = blockIdx.x * 64, m0 = blockIdx.y * 64;
    float acc[4][4] = {};
    for (int kk = 0; kk < K; kk += 16) {
#pragma unroll
        for (int l = 0; l < 4; l++) {
            int idx = tid + l * 256;
            int r = idx >> 4, c = idx & 15;
            As[r][c] = A[(size_t)(m0 + r) * K + kk + c];
        }
#pragma unroll
        for (int l = 0; l < 4; l++) {
            int idx = tid + l * 256;
            int kc = idx >> 6, nn = idx & 63;
            Bs[kc][nn] = ldf(B, (size_t)(kk + kc) * N + n0 + nn, f32);
        }
        __syncthreads();
#pragma unroll
        for (int kc = 0; kc < 16; kc++) {
            float a[4], bb[4];
#pragma unroll
            for (int i = 0; i < 4; i++) a[i] = As[ty * 4 + i][kc];
#pragma unroll
            for (int j = 0; j < 4; j++) bb[j] = Bs[kc][tx * 4 + j];
#pragma unroll
            for (int i = 0; i < 4; i++)
#pragma unroll
                for (int j = 0; j < 4; j++) acc[i][j] += a[i] * bb[j];
        }
        __syncthreads();
    }
#pragma unroll
    for (int i = 0; i < 4; i++) {
        int row = m0 + ty * 4 + i;
#pragma unroll
        for (int j = 0; j < 4; j++) {
            int col = n0 + tx * 4 + j;
            float r0 = resid ? ldf(resid, (size_t)row * N + col, f32) : 0.0f;
            C[(size_t)row * N + col] = acc[i][j] + r0;
        }
    }
}

// ---------------------------------------------------------------- attention (unchanged)
__global__ __launch_bounds__(64) void attn_kernel(const float* __restrict__ qkv,
                                                  float* __restrict__ y) {
    int q = blockIdx.x;
    int bh = blockIdx.y;
    int b = bh >> 4, h = bh & 15;
    int d = threadIdx.x;
    size_t nq = (size_t)b * TLEN + q;
    float qd = qkv[nq * 3 * DIMC + h * 64 + d] * 0.125f;
    const float* kbase = qkv + (size_t)b * TLEN * 3 * DIMC + DIMC + h * 64 + d;
    const float* vbase = kbase + DIMC;
    float m = -INFINITY, l = 0.f, acc = 0.f;
    for (int k = 0; k <= q; k++) {
        float p = qd * kbase[(size_t)k * 3 * DIMC];
#pragma unroll
        for (int mask = 32; mask > 0; mask >>= 1) p += __shfl_xor(p, mask);
        float vd = vbase[(size_t)k * 3 * DIMC];
        float mn = fmaxf(m, p);
        float alpha = __expf(m - mn);
        float w = __expf(p - mn);
        l = l * alpha + w;
        acc = acc * alpha + w * vd;
        m = mn;
    }
    y[nq * DIMC + h * 64 + d] = acc / l;
}

// ---------------------------------------------------------------- router (unchanged, fp32-exact)
__global__ __launch_bounds__(256) void router_kernel(const float* __restrict__ h2,
                                                     const void* __restrict__ wr,
                                                     int* topi, float* topw,
                                                     unsigned* counts, const int* flag) {
    int f32 = *flag;
    int n = blockIdx.x, tid = threadIdx.x;
    __shared__ float sm[NE][256];
    float p[NE] = {};
#pragma unroll
    for (int l = 0; l < 4; l++) {
        int dd = l * 256 + tid;
        float hv = h2[(size_t)n * DIMC + dd];
#pragma unroll
        for (int e = 0; e < NE; e++) p[e] += hv * ldf(wr, (size_t)dd * NE + e, f32);
    }
#pragma unroll
    for (int e = 0; e < NE; e++) sm[e][tid] = p[e];
    __syncthreads();
    for (int st = 128; st > 0; st >>= 1) {
        if (tid < st)
#pragma unroll
            for (int e = 0; e < NE; e++) sm[e][tid] += sm[e][tid + st];
        __syncthreads();
    }
    if (tid == 0) {
        float lg[NE];
#pragma unroll
        for (int e = 0; e < NE; e++) lg[e] = sm[e][0];
        int i0 = 0;
        for (int e = 1; e < NE; e++) if (lg[e] > lg[i0]) i0 = e;
        int i1 = -1;
        for (int e = 0; e < NE; e++)
            if (e != i0 && (i1 < 0 || lg[e] > lg[i1])) i1 = e;
        float e1 = __expf(lg[i1] - lg[i0]);
        float inv = 1.0f / (1.0f + e1);
        topi[n * 2] = i0; topi[n * 2 + 1] = i1;
        topw[n * 2] = inv; topw[n * 2 + 1] = e1 * inv;
        atomicAdd(&counts[i0], 1u);
        atomicAdd(&counts[i1], 1u);
    }
}

__global__ void offsets_kernel(const unsigned* counts, unsigned* offsets, unsigned* cursor) {
    if (threadIdx.x == 0 && blockIdx.x == 0) {
        unsigned s = 0;
        for (int e = 0; e < NE; e++) { offsets[e] = s; s += counts[e]; cursor[e] = 0u; }
    }
}

__global__ void scatter_kernel(const int* topi, const unsigned* offsets,
                               unsigned* cursor, int* perm) {
    int n = blockIdx.x * 256 + threadIdx.x;
    if (n >= NTOK) return;
    for (int s = 0; s < 2; s++) {
        int e = topi[n * 2 + s];
        unsigned pos = atomicAdd(&cursor[e], 1u);
        perm[offsets[e] + pos] = n * 2 + s;
    }
}

// ---------------------------------------------------------------- transpose+cast to bf16
// in: raw (flag dtype) [z][R][C]  ->  out bf16 [z][C][R]
__global__ __launch_bounds__(256) void transpose_kernel(const void* __restrict__ in,
                                                        short* __restrict__ out,
                                                        int R, int C, const int* flag) {
    int f32 = *flag;
    __shared__ short t[32][33];
    int r0 = blockIdx.y * 32, c0 = blockIdx.x * 32;
    size_t base = (size_t)blockIdx.z * R * C;
    int tx = threadIdx.x & 31, ty = threadIdx.x >> 5;   // 32 x 8
#pragma unroll
    for (int i = ty; i < 32; i += 8)
        t[i][tx] = f2b(ldf(in, base + (size_t)(r0 + i) * C + c0 + tx, f32));
    __syncthreads();
#pragma unroll
    for (int i = ty; i < 32; i += 8)
        out[base + (size_t)(c0 + i) * R + r0 + tx] = t[tx][i];
}

// ---------------------------------------------------------------- MFMA GEMM for MoE
// MODE 2: he[slot] = gelu(h2b[tok(slot)] @ w1t[e]^T + b1[e])   (A gathered, out bf16)
// MODE 3: moe[tok] += topw[slot] * (he[slot] @ w2t[e]^T)       (atomic epilogue)
// Bt layout: [e][N][K] (pre-transposed, contiguous-in-k fragments).
// Layouts (verified m89): A-frag A[m=lane&15][k=quad*8+j]; B-frag B[k=quad*8+j][n=lane&15];
// C/D col=lane&15, row=quad*4+reg.
template<int MODE>
__global__ __launch_bounds__(256) void mfma_gemm(
    const short* __restrict__ A, const short* __restrict__ Bt,
    short* __restrict__ Cb, const void* __restrict__ bias,
    const int* __restrict__ perm, const unsigned* __restrict__ counts,
    const unsigned* __restrict__ offsets, const float* __restrict__ topw,
    float* __restrict__ moe_out,
    int N, int K, const int* flag)
{
    int e = blockIdx.z;
    int m0 = blockIdx.y * 64, n0 = blockIdx.x * 64;
    int cnt = (int)counts[e];
    if (m0 >= cnt) return;
    unsigned off = offsets[e];
    __shared__ int tokL[64];
    __shared__ float wL[64];
    int tid = threadIdx.x;
    if (tid < 64) {
        int rr = m0 + tid; if (rr >= cnt) rr = cnt - 1;
        int pair = perm[off + rr];
        tokL[tid] = pair >> 1;
        wL[tid] = topw[pair];
    }
    __syncthreads();

    int w = tid >> 6, lane = tid & 63, quad = lane >> 4, l15 = lane & 15;
    int wm = (w >> 1) * 32, wn = (w & 1) * 32;
    int ko = quad * 8;

    const short *a0p, *a1p;
    if (MODE == 2) {
        a0p = A + (size_t)tokL[wm + l15] * K;
        a1p = A + (size_t)tokL[wm + l15 + 16] * K;
    } else {
        int r0 = m0 + wm + l15;      if (r0 >= cnt) r0 = cnt - 1;
        int r1 = m0 + wm + l15 + 16; if (r1 >= cnt) r1 = cnt - 1;
        a0p = A + ((size_t)off + r0) * K;
        a1p = A + ((size_t)off + r1) * K;
    }
    const short* b0p = Bt + (size_t)e * N * K + (size_t)(n0 + wn + l15) * K;
    const short* b1p = b0p + (size_t)16 * K;

    f32x4 acc00 = {0.f,0.f,0.f,0.f}, acc01 = acc00, acc10 = acc00, acc11 = acc00;
#pragma unroll 4
    for (int kk = 0; kk < K; kk += 32) {
        bf16x8 a0 = *(const bf16x8*)(a0p + kk + ko);
        bf16x8 a1 = *(const bf16x8*)(a1p + kk + ko);
        bf16x8 b0 = *(const bf16x8*)(b0p + kk + ko);
        bf16x8 b1 = *(const bf16x8*)(b1p + kk + ko);
        acc00 = __builtin_amdgcn_mfma_f32_16x16x32_bf16(a0, b0, acc00, 0, 0, 0);
        acc01 = __builtin_amdgcn_mfma_f32_16x16x32_bf16(a0, b1, acc01, 0, 0, 0);
        acc10 = __builtin_amdgcn_mfma_f32_16x16x32_bf16(a1, b0, acc10, 0, 0, 0);
        acc11 = __builtin_amdgcn_mfma_f32_16x16x32_bf16(a1, b1, acc11, 0, 0, 0);
    }

    int f32 = (MODE == 2) ? *flag : 0;
#pragma unroll
    for (int mi = 0; mi < 2; mi++) {
#pragma unroll
        for (int ni = 0; ni < 2; ni++) {
            f32x4 acc = (mi == 0) ? (ni == 0 ? acc00 : acc01)
                                  : (ni == 0 ? acc10 : acc11);
            int col = n0 + wn + ni * 16 + l15;
#pragma unroll
            for (int reg = 0; reg < 4; reg++) {
                int row_local = wm + mi * 16 + quad * 4 + reg;
                if (m0 + row_local >= cnt) continue;
                float val = acc[reg];
                if (MODE == 2) {
                    val += ldf(bias, (size_t)e * N + col, f32);
                    val = 0.5f * val * (1.0f + erff(val * 0.70710678118f));
                    Cb[((size_t)off + m0 + row_local) * N + col] = f2b(val);
                } else {
                    int tok = tokL[row_local];
                    atomicAdd(&moe_out[(size_t)tok * N + col], val * wL[row_local]);
                }
            }
        }
    }
}

// ---------------------------------------------------------------- final: out = x2 + moe + sum_s w_s*b2[e_s]
__global__ void final_kernel(const float* x2, const float* moe,
                             const int* topi, const float* topw,
                             const void* b2, void* out, const int* flag) {
    int f32 = *flag;
    int i = blockIdx.x * 256 + threadIdx.x;
    int n = i >> 10, c = i & 1023;
    float v = x2[i] + moe[i];
#pragma unroll
    for (int s = 0; s < 2; s++)
        v += topw[n * 2 + s] * ldf(b2, (size_t)topi[n * 2 + s] * DIMC + c, f32);
    if (f32) ((float*)out)[i] = v;
    else     ((bf16*)out)[i] = __float2bfloat16(v);
}

// ================================================================ launch
extern "C" void kernel_launch(void* const* d_in, const int* in_sizes, int n_in,
                              void* d_out, int out_size, void* d_ws, size_t ws_size,
                              hipStream_t stream) {
    const void* x      = d_in[0];
    const void* ln1_g  = d_in[1];
    const void* ln1_b  = d_in[2];
    const void* w_attn = d_in[3];
    const void* w_proj = d_in[4];
    const void* ln2_g  = d_in[5];
    const void* ln2_b  = d_in[6];
    const void* w_rout = d_in[7];
    const void* w1     = d_in[8];
    const void* b1     = d_in[9];
    const void* w2     = d_in[10];
    const void* b2     = d_in[11];

    const size_t MT = (size_t)NTOK * DIMC;   // 4 M elements
    float* ws   = (float*)d_ws;
    float* h    = ws;                // MT
    float* qkv  = ws + MT;           // 3*MT   (dead after attn; he aliases here)
    float* y    = ws + 4 * MT;       // MT     (dead after proj)
    float* x2   = ws + 5 * MT;       // MT
    float* h2   = ws + 6 * MT;       // MT
    float* moe  = ws + 7 * MT;       // MT
    float* small = ws + 8 * MT;
    int*      topi    = (int*)small;                   // 8192
    float*    topw    = (float*)(topi + 2 * NTOK);     // 8192
    unsigned* counts  = (unsigned*)(topw + 2 * NTOK);  // 8
    unsigned* offsets = counts + NE;                   // 8
    unsigned* cursor  = offsets + NE;                  // 8
    int*      perm    = (int*)(cursor + NE);           // 8192
    int*      flag    = (int*)(perm + 2 * NTOK);       // 1
    // new bf16 buffers
    short* h2b  = (short*)(ws + 8 * MT + 32768);                 // MT bf16 = 8 MB
    short* w12t = (short*)(ws + 8 * MT + 32768 + MT / 2);        // 8*4096*1024 bf16 = 64 MB (w1t then w2t)
    short* he   = (short*)(ws + MT);                             // 8192*4096 bf16 = 64 MB (aliases qkv+y)

    // 0. detect input dtype
    detect_kernel<<<1, 64, 0, stream>>>(x, flag);
    // 1. zero moe accumulator + expert counts
    zero_kernel<<<dim3((MT + 255) / 256), 256, 0, stream>>>(moe, counts);
    // 2. LN1 -> h (fp32)
    ln_kernel<<<NTOK, 256, 0, stream>>>(x, nullptr, ln1_g, ln1_b, h, nullptr, flag);
    // 3. qkv = h @ w_attn
    gemm_f32<<<dim3(3 * DIMC / 64, NTOK / 64), 256, 0, stream>>>(h, w_attn, nullptr, qkv,
                                                                 NTOK, 3 * DIMC, DIMC, flag);
    // 4. attention
    attn_kernel<<<dim3(TLEN, NBATCH * NHEADS), 64, 0, stream>>>(qkv, y);
    // 5. x2 = x + y @ w_proj
    gemm_f32<<<dim3(DIMC / 64, NTOK / 64), 256, 0, stream>>>(y, w_proj, x, x2,
                                                             NTOK, DIMC, DIMC, flag);
    // 6. LN2 -> h2 (fp32, router) + h2b (bf16, experts)
    ln_kernel<<<NTOK, 256, 0, stream>>>(nullptr, x2, ln2_g, ln2_b, h2, h2b, flag);
    // 7. router + top-2 (fp32-exact, unchanged)
    router_kernel<<<NTOK, 256, 0, stream>>>(h2, w_rout, topi, topw, counts, flag);
    // 8. prefix offsets
    offsets_kernel<<<1, 64, 0, stream>>>(counts, offsets, cursor);
    // 9. scatter token-slot ids by expert
    scatter_kernel<<<NTOK / 256, 256, 0, stream>>>(topi, offsets, cursor, perm);
    // 10. w1t[e][HIDN][DIMC] = w1[e][DIMC][HIDN]^T  (bf16)
    transpose_kernel<<<dim3(HIDN / 32, DIMC / 32, NE), 256, 0, stream>>>(w1, w12t, DIMC, HIDN, flag);
    // 11. GEMM1: he = gelu(gather(h2b) @ w1t^T + b1)
    mfma_gemm<2><<<dim3(HIDN / 64, NTOK / 64, NE), 256, 0, stream>>>(
        h2b, w12t, he, b1, perm, counts, offsets, topw, nullptr, HIDN, DIMC, flag);
    // 12. w2t[e][DIMC][HIDN] = w2[e][HIDN][DIMC]^T  (bf16, reuses w1t buffer)
    transpose_kernel<<<dim3(DIMC / 32, HIDN / 32, NE), 256, 0, stream>>>(w2, w12t, HIDN, DIMC, flag);
    // 13. GEMM2: moe[tok] += topw * (he @ w2t^T)
    mfma_gemm<3><<<dim3(DIMC / 64, NTOK / 64, NE), 256, 0, stream>>>(
        he, w12t, nullptr, nullptr, perm, counts, offsets, topw, moe, DIMC, HIDN, flag);
    // 14. out = x2 + moe + sum_s w_s * b2[e_s]
    final_kernel<<<dim3((MT + 255) / 256), 256, 0, stream>>>(x2, moe, topi, topw, b2,
                                                             (void*)d_out, flag);
}